// Round 16
// baseline (215.376 us; speedup 1.0000x reference)
//
#include <hip/hip_runtime.h>
#include <hip/hip_bf16.h>
#include <cstdint>
#include <cstddef>

// ---------------- problem constants ----------------
constexpr int Bn   = 8;
constexpr int Hn   = 64;
constexpr int Wn   = 64;
constexpr int Cn   = 256;
constexpr int OUTC = 1024;
constexpr int HPAD = 66;   // 64 + 2 halo
constexpr int WPAD = 66;
#define EPS 1e-5f

typedef __attribute__((ext_vector_type(4))) float f32x4;
typedef __attribute__((ext_vector_type(16))) float f32x16;
typedef __bf16 bf16x8 __attribute__((ext_vector_type(8)));

// ---------------- K0: conv_w [3][3][256][1024] f32 -> wT [9][1024][256] bf16 ----------------
__global__ __launch_bounds__(256) void k0_transpose_w(const float* __restrict__ conv_w,
                                                      __hip_bfloat16* __restrict__ wT) {
    __shared__ float tile[64][65];
    const int tap = blockIdx.x;        // 0..8
    const int ct  = blockIdx.y;        // c-tile 0..3  (64 ch)
    const int ot  = blockIdx.z;        // o-tile 0..15 (64 out)
    const int t   = threadIdx.x;
    const int lo  = t & 63;
    const int cq  = t >> 6;            // 0..3

#pragma unroll
    for (int k = 0; k < 16; ++k) {
        int ci = k * 4 + cq;
        tile[lo][ci] = conv_w[((size_t)(tap * Cn + ct * 64 + ci)) * OUTC + ot * 64 + lo];
    }
    __syncthreads();
#pragma unroll
    for (int k = 0; k < 16; ++k) {
        int oo = k * 4 + cq;
        wT[((size_t)(tap * OUTC + ot * 64 + oo)) * Cn + ct * 64 + lo] =
            __float2bfloat16(tile[oo][lo]);
    }
}

// ---------------- K1: per-(b,h) sums over w (1024 thr: 4 w-slices x 256 ch) ----------------
__global__ __launch_bounds__(1024) void k1_stats_partial(const float* __restrict__ x,
                                                         float* __restrict__ ps,
                                                         float* __restrict__ pq) {
    __shared__ float sb[2][4][256];
    const int bh = blockIdx.x;          // b*64 + h
    const int tid = threadIdx.x;
    const int c = tid & 255;
    const int s = tid >> 8;             // 0..3
    const float* row = x + (size_t)bh * Wn * Cn + (size_t)s * 16 * Cn + c;
    float sm = 0.f, q = 0.f;
#pragma unroll
    for (int w = 0; w < 16; ++w) {
        float v = row[(size_t)w * Cn];
        sm += v; q += v * v;
    }
    sb[0][s][c] = sm; sb[1][s][c] = q;
    __syncthreads();
    if (s == 0) {
        float S = 0.f, Q = 0.f;
#pragma unroll
        for (int k = 0; k < 4; ++k) { S += sb[0][k][c]; Q += sb[1][k][c]; }
        ps[bh * Cn + c] = S;
        pq[bh * Cn + c] = Q;
    }
}

// ---------------- K2: reduce over h, produce scale/shift (1024 thr) ----------------
__global__ __launch_bounds__(1024) void k2_stats_final(const float* __restrict__ ps,
                                                       const float* __restrict__ pq,
                                                       float* __restrict__ scale,
                                                       float* __restrict__ shift) {
    __shared__ float sb[2][4][256];
    const int b = blockIdx.x;
    const int tid = threadIdx.x;
    const int c = tid & 255;
    const int qd = tid >> 8;            // 0..3, each sums 16 h
    float S = 0.f, Q = 0.f;
#pragma unroll 4
    for (int i = 0; i < 16; ++i) {
        int h = qd * 16 + i;
        S += ps[(b * Hn + h) * Cn + c];
        Q += pq[(b * Hn + h) * Cn + c];
    }
    sb[0][qd][c] = S; sb[1][qd][c] = Q;
    __syncthreads();
    if (qd == 0) {
        float s2 = 0.f, q2 = 0.f;
#pragma unroll
        for (int k = 0; k < 4; ++k) { s2 += sb[0][k][c]; q2 += sb[1][k][c]; }
        const float inv = 1.f / (float)(Hn * Wn);
        float mean = s2 * inv;
        float var  = fmaxf(q2 * inv - mean * mean, 0.f);
        float sc   = 1.f / (sqrtf(var) + EPS);
        scale[b * Cn + c] = sc;
        shift[b * Cn + c] = -mean * sc;
    }
}

// ---------------- K3: norm + depthwise 3x3 + pointwise + bias -> t_pad bf16 ----------------
// grid: B*HPAD*4 (4 w-quads of 16 output cols each) — R11 version (R15 vec regressed)
__global__ __launch_bounds__(256) void k3_dwconv(const float* __restrict__ x,
                                                 const float* __restrict__ w_sp,
                                                 const float* __restrict__ w_pw,
                                                 const float* __restrict__ bias,
                                                 const float* __restrict__ scale,
                                                 const float* __restrict__ shift,
                                                 __hip_bfloat16* __restrict__ tpad) {
    const int bq = blockIdx.x;
    const int wq = bq & 3;
    const int bh = bq >> 2;
    const int b  = bh / HPAD;
    const int hp = bh - b * HPAD;       // 0..65
    const int c  = threadIdx.x;
    __hip_bfloat16* orow = tpad + ((size_t)(b * HPAD + hp)) * WPAD * Cn + c;
    const __hip_bfloat16 z = __float2bfloat16(0.f);

    if (hp == 0 || hp == HPAD - 1) {
        int wlo = wq * 17, whi = wlo + 17 < WPAD ? wlo + 17 : WPAD;
        for (int wp = wlo; wp < whi; ++wp) orow[(size_t)wp * Cn] = z;
        return;
    }
    const int h = hp - 1;
    const float sc = scale[b * Cn + c];
    const float sh = shift[b * Cn + c];
    float w9[9];
#pragma unroll
    for (int k = 0; k < 9; ++k) w9[k] = w_sp[(b * 9 + k) * Cn + c];
    const float pw = w_pw[b * Cn + c];
    const float bv = bias[b * Cn + c];
    const float* xb = x + (size_t)b * Hn * Wn * Cn + c;

    bool rv[3];
#pragma unroll
    for (int r = 0; r < 3; ++r) { int rr = h - 1 + r; rv[r] = (rr >= 0 && rr < Hn); }

    if (wq == 0) orow[0] = z;
    if (wq == 3) orow[(size_t)(WPAD - 1) * Cn] = z;

    const int w0 = wq * 16;
    float win[3][3];
#pragma unroll
    for (int r = 0; r < 3; ++r) {
        win[r][0] = (rv[r] && w0 > 0)
                    ? (xb[((size_t)(h - 1 + r) * Wn + (w0 - 1)) * Cn] * sc + sh) : 0.f;
        win[r][1] = rv[r] ? (xb[((size_t)(h - 1 + r) * Wn + w0) * Cn] * sc + sh) : 0.f;
    }
    for (int i = 0; i < 16; ++i) {
        const int w = w0 + i;
#pragma unroll
        for (int r = 0; r < 3; ++r)
            win[r][2] = (rv[r] && (w + 1) < Wn)
                        ? (xb[((size_t)(h - 1 + r) * Wn + (w + 1)) * Cn] * sc + sh) : 0.f;
        float y = 0.f;
#pragma unroll
        for (int r = 0; r < 3; ++r)
#pragma unroll
            for (int qq = 0; qq < 3; ++qq)
                y += win[r][qq] * w9[r * 3 + qq];
        orow[(size_t)(w + 1) * Cn] = __float2bfloat16(y * pw + bv);
#pragma unroll
        for (int r = 0; r < 3; ++r) { win[r][0] = win[r][1]; win[r][1] = win[r][2]; }
    }
}

// ---------------- K4: implicit-GEMM, 256x256, BK=32, 32x32x16 + K-MAJOR LDS + reg-staging --
// 512 thr = 8 waves (2m x 4n), per-wave 128x64; R6-proven minimal-sync 2-step body.
// K-MAJOR LDS: addr = kgroup*4096 + row*16 (A base 0, B base 16384; 4 kgroups of 8 bf16).
// 32-row fragment read = two 512B CONTIGUOUS runs (lanes 0-31 / 32-63) -> conflict-free
// (R3/R5/R15's 1.416e7 conflicts came from 32-row reads of the row-pair/XOR layout).
// Staging must therefore be reg-staged (HK pattern): global_load row-major coalesced
// (thread t = row t>>1, 32B half t&1) -> ds_write_b128 to k-major (per-wave writes are
// two 512B contiguous runs -> conflict-free). Loads issue at body top, vmcnt(0) waited
// ~1 MFMA-cluster later; writes land mid-body into bufs t+2,t+3 (disjoint from reads
// t0,t1); lgkmcnt(0)+barrier at body end publishes them. kk-outer MFMA order.
constexpr int KSTEPS = 72;              // 9 taps x (256/32)
constexpr int BUFSZ  = 32768;           // A 16KB (4 kgroups x 4KB) + B 16KB

__global__ __launch_bounds__(512, 2) void k4_gemm(const __hip_bfloat16* __restrict__ tpad,
                                                  const __hip_bfloat16* __restrict__ wT,
                                                  const float* __restrict__ conv_b,
                                                  float* __restrict__ out) {
    __shared__ __align__(16) char smem[4 * BUFSZ];   // 128 KB

    const int tid  = threadIdx.x;
    const int lane = tid & 63;
    const int wv   = tid >> 6;          // 0..7
    const int wm   = wv >> 2;           // 0..1
    const int wn   = wv & 3;            // 0..3
    const int l31  = lane & 31;
    const int kh2  = lane >> 5;         // k-octet half select

    // XCD-chunked mapping (bijective: 8 x 16 x 4 = 512)
    const int bid = blockIdx.x;
    const int mt  = (bid & 7) * 16 + ((bid >> 3) & 15);   // 0..127
    const int nt  = bid >> 7;                             // 0..3
    const int pixbase = mt * 256;
    const int b       = mt >> 4;
    const int hbase   = (mt & 15) * 4;
    const int obase   = nt * 256;

    // ---- reg-staging assignment: thread t -> row srow = t>>1, 32B half = t&1 ----
    const int srow  = tid >> 1;         // 0..255 (pixel row for A, out-ch for B)
    const int shalf = tid & 1;
    const int ahh = hbase + (srow >> 6);
    const int aww = srow & 63;
    const int aGbase = ((b * HPAD + ahh) * WPAD + aww) * Cn + shalf * 16;  // elements
    const int bGbase = (obase + srow) * Cn + shalf * 16;
    // LDS k-major dest: kgroups (2*shalf, 2*shalf+1), row srow
    const int aDst = (2 * shalf) * 4096 + srow * 16;
    const int bDst = 16384 + (2 * shalf) * 4096 + srow * 16;

    auto issueLoads = [&](int s, bf16x8& a0, bf16x8& a1, bf16x8& b0, bf16x8& b1) {
        const int tap = s >> 3, ks = s & 7;
        const int kh  = tap / 3, kw = tap - 3 * kh;
        const __hip_bfloat16* aS = tpad + (kh * WPAD + kw) * Cn + ks * 32 + aGbase;
        const __hip_bfloat16* bS = wT + (size_t)tap * (OUTC * Cn) + ks * 32 + bGbase;
        a0 = *(const bf16x8*)(aS);      // octet 2*shalf
        a1 = *(const bf16x8*)(aS + 8);  // octet 2*shalf+1
        b0 = *(const bf16x8*)(bS);
        b1 = *(const bf16x8*)(bS + 8);
    };
    auto writeStage = [&](int s, bf16x8 a0, bf16x8 a1, bf16x8 b0, bf16x8 b1) {
        char* buf = smem + (s & 3) * BUFSZ;
        *(bf16x8*)(buf + aDst)        = a0;
        *(bf16x8*)(buf + aDst + 4096) = a1;
        *(bf16x8*)(buf + bDst)        = b0;
        *(bf16x8*)(buf + bDst + 4096) = b1;
    };

    // ---- fragment read bases (k-major, contiguous per 32-lane half) ----
    const int aRow = (wm * 128 + l31) * 16;           // + mf*512 + (kk*2+kh2)*4096
    const int bRow = 16384 + (wn * 64 + l31) * 16;    // + nf*512 + (kk*2+kh2)*4096
    const int kg0 = kh2 * 4096;        // kk = 0
    const int kg1 = (2 + kh2) * 4096;  // kk = 1

    f32x16 acc[4][2] = {};

    auto substep = [&](int t) {
        char* buf = smem + (t & 3) * BUFSZ;
        bf16x8 bfr[2][2], afr[4][2];
#pragma unroll
        for (int nf = 0; nf < 2; ++nf) {
            bfr[nf][0] = *(const bf16x8*)(buf + bRow + nf * 512 + kg0);
            bfr[nf][1] = *(const bf16x8*)(buf + bRow + nf * 512 + kg1);
        }
#pragma unroll
        for (int mf = 0; mf < 4; ++mf) {
            afr[mf][0] = *(const bf16x8*)(buf + aRow + mf * 512 + kg0);
            afr[mf][1] = *(const bf16x8*)(buf + aRow + mf * 512 + kg1);
        }
        __builtin_amdgcn_s_setprio(1);
#pragma unroll
        for (int kk = 0; kk < 2; ++kk)      // kk OUTER: dependent pairs 8 apart
#pragma unroll
            for (int mf = 0; mf < 4; ++mf)
#pragma unroll
                for (int nf = 0; nf < 2; ++nf)
                    acc[mf][nf] = __builtin_amdgcn_mfma_f32_32x32x16_bf16(
                        afr[mf][kk], bfr[nf][kk], acc[mf][nf], 0, 0, 0);
        __builtin_amdgcn_s_setprio(0);
    };

    bf16x8 pa0, pa1, pb0, pb1, qa0, qa1, qb0, qb1;

    // ---- prologue: load+write K-steps 0,1 ----
    issueLoads(0, pa0, pa1, pb0, pb1);
    issueLoads(1, qa0, qa1, qb0, qb1);
    asm volatile("s_waitcnt vmcnt(0)" ::: "memory");
    writeStage(0, pa0, pa1, pb0, pb1);
    writeStage(1, qa0, qa1, qb0, qb1);
    asm volatile("s_waitcnt lgkmcnt(0)" ::: "memory");
    __builtin_amdgcn_s_barrier();
    __builtin_amdgcn_sched_barrier(0);

#pragma unroll 1
    for (int body = 0; body < KSTEPS / 2; ++body) {
        const int t0 = 2 * body;
        const bool st = (t0 + 2 < KSTEPS);
        if (st) {
            issueLoads(t0 + 2, pa0, pa1, pb0, pb1);
            issueLoads(t0 + 3, qa0, qa1, qb0, qb1);
        }
        substep(t0);
        __builtin_amdgcn_sched_barrier(0);
        if (st) {
            // loads issued ~1 MFMA-cluster ago -> no stall; write bufs t0+2,t0+3
            asm volatile("s_waitcnt vmcnt(0)" ::: "memory");
            writeStage(t0 + 2, pa0, pa1, pb0, pb1);
            writeStage(t0 + 3, qa0, qa1, qb0, qb1);
        }
        substep(t0 + 1);
        __builtin_amdgcn_sched_barrier(0);
        if (body + 1 < KSTEPS / 2) {
            asm volatile("s_waitcnt lgkmcnt(0)" ::: "memory");  // ds_writes published
            __builtin_amdgcn_s_barrier();
            __builtin_amdgcn_sched_barrier(0);
        }
    }

    // ---- epilogue: C frag col = l31, row = (j&3) + 8*(j>>2) + 4*kh2 (m74/m101) ----
    float cb2[2];
#pragma unroll
    for (int nf = 0; nf < 2; ++nf) cb2[nf] = conv_b[obase + wn * 64 + nf * 32 + l31];
#pragma unroll
    for (int mf = 0; mf < 4; ++mf) {
#pragma unroll
        for (int j = 0; j < 16; ++j) {
            int row = (j & 3) + 8 * (j >> 2) + 4 * kh2;
            int r = pixbase + wm * 128 + mf * 32 + row;
            float* orow = out + (size_t)r * OUTC + obase + wn * 64 + l31;
            orow[0]  = acc[mf][0][j] + cb2[0];
            orow[32] = acc[mf][1][j] + cb2[1];
        }
    }
}

// ---------------- launch ----------------
extern "C" void kernel_launch(void* const* d_in, const int* in_sizes, int n_in,
                              void* d_out, int out_size, void* d_ws, size_t ws_size,
                              hipStream_t stream) {
    const float* x      = (const float*)d_in[0];
    const float* w_sp   = (const float*)d_in[1];
    const float* w_pw   = (const float*)d_in[2];
    const float* bias   = (const float*)d_in[3];
    const float* conv_w = (const float*)d_in[4];
    const float* conv_b = (const float*)d_in[5];
    float* out = (float*)d_out;

    char* ws = (char*)d_ws;
    __hip_bfloat16* wT    = (__hip_bfloat16*)(ws);
    float*          ps    = (float*)(ws + 4718592);
    float*          pq    = (float*)(ws + 4718592 + 524288);
    float*          scale = (float*)(ws + 5767168);
    float*          shift = (float*)(ws + 5775360);
    __hip_bfloat16* tpad  = (__hip_bfloat16*)(ws + 5783552);

    k0_transpose_w<<<dim3(9, 4, 16), 256, 0, stream>>>(conv_w, wT);
    k1_stats_partial<<<Bn * Hn, 1024, 0, stream>>>(x, ps, pq);
    k2_stats_final<<<Bn, 1024, 0, stream>>>(ps, pq, scale, shift);
    k3_dwconv<<<Bn * HPAD * 4, 256, 0, stream>>>(x, w_sp, w_pw, bias, scale, shift, tpad);
    k4_gemm<<<512, 512, 0, stream>>>(tpad, wT, conv_b, out);
}

// Round 17
// 168.669 us; speedup vs baseline: 1.2769x; 1.2769x over previous
//
#include <hip/hip_runtime.h>
#include <hip/hip_bf16.h>
#include <cstdint>
#include <cstddef>

// ---------------- problem constants ----------------
constexpr int Bn   = 8;
constexpr int Hn   = 64;
constexpr int Wn   = 64;
constexpr int Cn   = 256;
constexpr int OUTC = 1024;
constexpr int HPAD = 66;   // 64 + 2 halo
constexpr int WPAD = 66;
#define EPS 1e-5f

typedef __attribute__((ext_vector_type(4))) float f32x4;
typedef __bf16 bf16x8 __attribute__((ext_vector_type(8)));

// ---------------- helpers ----------------
__device__ __forceinline__ void gload_lds16(const void* g, void* l) {
    __builtin_amdgcn_global_load_lds(
        (__attribute__((address_space(1))) void*)g,
        (__attribute__((address_space(3))) void*)l,
        16, 0, 0);
}

// ---------------- K0: conv_w [3][3][256][1024] f32 -> wT [9][1024][256] bf16 ----------------
__global__ __launch_bounds__(256) void k0_transpose_w(const float* __restrict__ conv_w,
                                                      __hip_bfloat16* __restrict__ wT) {
    __shared__ float tile[64][65];
    const int tap = blockIdx.x;        // 0..8
    const int ct  = blockIdx.y;        // c-tile 0..3  (64 ch)
    const int ot  = blockIdx.z;        // o-tile 0..15 (64 out)
    const int t   = threadIdx.x;
    const int lo  = t & 63;
    const int cq  = t >> 6;            // 0..3

#pragma unroll
    for (int k = 0; k < 16; ++k) {
        int ci = k * 4 + cq;
        tile[lo][ci] = conv_w[((size_t)(tap * Cn + ct * 64 + ci)) * OUTC + ot * 64 + lo];
    }
    __syncthreads();
#pragma unroll
    for (int k = 0; k < 16; ++k) {
        int oo = k * 4 + cq;
        wT[((size_t)(tap * OUTC + ot * 64 + oo)) * Cn + ct * 64 + lo] =
            __float2bfloat16(tile[oo][lo]);
    }
}

// ---------------- K1: per-(b,h) sums over w (1024 thr: 4 w-slices x 256 ch) ----------------
__global__ __launch_bounds__(1024) void k1_stats_partial(const float* __restrict__ x,
                                                         float* __restrict__ ps,
                                                         float* __restrict__ pq) {
    __shared__ float sb[2][4][256];
    const int bh = blockIdx.x;          // b*64 + h
    const int tid = threadIdx.x;
    const int c = tid & 255;
    const int s = tid >> 8;             // 0..3
    const float* row = x + (size_t)bh * Wn * Cn + (size_t)s * 16 * Cn + c;
    float sm = 0.f, q = 0.f;
#pragma unroll
    for (int w = 0; w < 16; ++w) {
        float v = row[(size_t)w * Cn];
        sm += v; q += v * v;
    }
    sb[0][s][c] = sm; sb[1][s][c] = q;
    __syncthreads();
    if (s == 0) {
        float S = 0.f, Q = 0.f;
#pragma unroll
        for (int k = 0; k < 4; ++k) { S += sb[0][k][c]; Q += sb[1][k][c]; }
        ps[bh * Cn + c] = S;
        pq[bh * Cn + c] = Q;
    }
}

// ---------------- K2: reduce over h, produce scale/shift (1024 thr) ----------------
__global__ __launch_bounds__(1024) void k2_stats_final(const float* __restrict__ ps,
                                                       const float* __restrict__ pq,
                                                       float* __restrict__ scale,
                                                       float* __restrict__ shift) {
    __shared__ float sb[2][4][256];
    const int b = blockIdx.x;
    const int tid = threadIdx.x;
    const int c = tid & 255;
    const int qd = tid >> 8;            // 0..3, each sums 16 h
    float S = 0.f, Q = 0.f;
#pragma unroll 4
    for (int i = 0; i < 16; ++i) {
        int h = qd * 16 + i;
        S += ps[(b * Hn + h) * Cn + c];
        Q += pq[(b * Hn + h) * Cn + c];
    }
    sb[0][qd][c] = S; sb[1][qd][c] = Q;
    __syncthreads();
    if (qd == 0) {
        float s2 = 0.f, q2 = 0.f;
#pragma unroll
        for (int k = 0; k < 4; ++k) { s2 += sb[0][k][c]; q2 += sb[1][k][c]; }
        const float inv = 1.f / (float)(Hn * Wn);
        float mean = s2 * inv;
        float var  = fmaxf(q2 * inv - mean * mean, 0.f);
        float sc   = 1.f / (sqrtf(var) + EPS);
        scale[b * Cn + c] = sc;
        shift[b * Cn + c] = -mean * sc;
    }
}

// ---------------- K3: norm + depthwise 3x3 + pointwise + bias -> t_pad bf16 ----------------
// grid: B*HPAD*4 (4 w-quads of 16 output cols each)
__global__ __launch_bounds__(256) void k3_dwconv(const float* __restrict__ x,
                                                 const float* __restrict__ w_sp,
                                                 const float* __restrict__ w_pw,
                                                 const float* __restrict__ bias,
                                                 const float* __restrict__ scale,
                                                 const float* __restrict__ shift,
                                                 __hip_bfloat16* __restrict__ tpad) {
    const int bq = blockIdx.x;
    const int wq = bq & 3;
    const int bh = bq >> 2;
    const int b  = bh / HPAD;
    const int hp = bh - b * HPAD;       // 0..65
    const int c  = threadIdx.x;
    __hip_bfloat16* orow = tpad + ((size_t)(b * HPAD + hp)) * WPAD * Cn + c;
    const __hip_bfloat16 z = __float2bfloat16(0.f);

    if (hp == 0 || hp == HPAD - 1) {
        int wlo = wq * 17, whi = wlo + 17 < WPAD ? wlo + 17 : WPAD;
        for (int wp = wlo; wp < whi; ++wp) orow[(size_t)wp * Cn] = z;
        return;
    }
    const int h = hp - 1;
    const float sc = scale[b * Cn + c];
    const float sh = shift[b * Cn + c];
    float w9[9];
#pragma unroll
    for (int k = 0; k < 9; ++k) w9[k] = w_sp[(b * 9 + k) * Cn + c];
    const float pw = w_pw[b * Cn + c];
    const float bv = bias[b * Cn + c];
    const float* xb = x + (size_t)b * Hn * Wn * Cn + c;

    bool rv[3];
#pragma unroll
    for (int r = 0; r < 3; ++r) { int rr = h - 1 + r; rv[r] = (rr >= 0 && rr < Hn); }

    if (wq == 0) orow[0] = z;
    if (wq == 3) orow[(size_t)(WPAD - 1) * Cn] = z;

    const int w0 = wq * 16;
    float win[3][3];
#pragma unroll
    for (int r = 0; r < 3; ++r) {
        win[r][0] = (rv[r] && w0 > 0)
                    ? (xb[((size_t)(h - 1 + r) * Wn + (w0 - 1)) * Cn] * sc + sh) : 0.f;
        win[r][1] = rv[r] ? (xb[((size_t)(h - 1 + r) * Wn + w0) * Cn] * sc + sh) : 0.f;
    }
    for (int i = 0; i < 16; ++i) {
        const int w = w0 + i;
#pragma unroll
        for (int r = 0; r < 3; ++r)
            win[r][2] = (rv[r] && (w + 1) < Wn)
                        ? (xb[((size_t)(h - 1 + r) * Wn + (w + 1)) * Cn] * sc + sh) : 0.f;
        float y = 0.f;
#pragma unroll
        for (int r = 0; r < 3; ++r)
#pragma unroll
            for (int qq = 0; qq < 3; ++qq)
                y += win[r][qq] * w9[r * 3 + qq];
        orow[(size_t)(w + 1) * Cn] = __float2bfloat16(y * pw + bv);
#pragma unroll
        for (int r = 0; r < 3; ++r) { win[r][0] = win[r][1]; win[r][1] = win[r][2]; }
    }
}

// ---------------- K4: implicit-GEMM, 256x256, BK=32, ASYMMETRIC WAVE ROLES (best: R11) ----
// 512 thr = 8 waves (2m x 4n), per-wave 128x64. Conflict-free LDS (2 pixels/128B row,
// slot ^= (row&7), gload-linear dest + inverse-swizzled global source). 4 bufs x 32KB.
// Body = 2 K-steps {t0,t1}, both bufs valid all body. Wave-role asymmetry:
//   E-waves (wm=0): R(t0) M(t0) R(t1) M(t1)
//   O-waves (wm=1): R(t0)+R_A(t1) M(t0) R_B(t1) M(t1)
// Body end: sched_barrier + vmcnt(0) (long-slack drain of stage t0+2,t0+3) + barrier.
// Measured (R11): k4 141.6us, MfmaUtil 48.0, conflicts 0 — best of 11 k4 variants.
// (Zero-overlap additive model: step = MFMA 1242 + LDS 96KB rd + 32KB stage + sync
//  = ~2370 cyc; every schedule/layout variant tried lands at or above this floor.)
constexpr int KSTEPS = 72;              // 9 taps x (256/32)
constexpr int BUFSZ  = 32768;           // A 16KB + B 16KB

__global__ __launch_bounds__(512, 2) void k4_gemm(const __hip_bfloat16* __restrict__ tpad,
                                                  const __hip_bfloat16* __restrict__ wT,
                                                  const float* __restrict__ conv_b,
                                                  float* __restrict__ out) {
    __shared__ __align__(16) char smem[4 * BUFSZ];   // 128 KB

    const int tid  = threadIdx.x;
    const int lane = tid & 63;
    const int wv   = tid >> 6;          // 0..7
    const int wm   = wv >> 2;           // 0..1  (E/O role split: 1 E + 1 O per SIMD)
    const int wn   = wv & 3;            // 0..3
    const int g    = lane >> 4, l15 = lane & 15;

    // XCD-chunked mapping (bijective: 8 x 16 x 4 = 512)
    const int bid = blockIdx.x;
    const int mt  = (bid & 7) * 16 + ((bid >> 3) & 15);   // 0..127
    const int nt  = bid >> 7;                             // 0..3
    const int pixbase = mt * 256;
    const int b       = mt >> 4;
    const int hbase   = (mt & 15) * 4;
    const int obase   = nt * 256;

    // ---- staging source offsets (proven): unit u = j*512 + tid ----
    int aoff[2], boff[2];
#pragma unroll
    for (int j = 0; j < 2; ++j) {
        int u = j * 512 + tid;
        int r = u >> 3, p = u & 7;
        int l = p ^ (r & 7);
        int pix = 2 * r + (l >> 2);
        int hh  = hbase + (pix >> 6);
        int ww  = pix & 63;
        aoff[j] = ((b * HPAD + hh) * WPAD + ww) * Cn + (l & 3) * 8;
        boff[j] = (obase + 2 * r + (l >> 2)) * Cn + (l & 3) * 8;
    }

    auto stageS = [&](int s) {
        const int tap = s >> 3, ks = s & 7;
        const int kh  = tap / 3, kw = tap - 3 * kh;
        const __hip_bfloat16* aS = tpad + ((kh * WPAD + kw) * Cn + ks * 32);
        const __hip_bfloat16* bS = wT + (size_t)tap * (OUTC * Cn) + ks * 32;
        char* buf = smem + (s & 3) * BUFSZ;
        gload_lds16(aS + aoff[0], buf + (size_t)(0 * 512 + wv * 64) * 16);
        gload_lds16(aS + aoff[1], buf + (size_t)(1 * 512 + wv * 64) * 16);
        gload_lds16(bS + boff[0], buf + 16384 + (size_t)(0 * 512 + wv * 64) * 16);
        gload_lds16(bS + boff[1], buf + 16384 + (size_t)(1 * 512 + wv * 64) * 16);
    };

    // ---- per-lane fragment read offsets (conflict-free, m-invariant XOR) ----
    const int slot = ((((l15 & 1) << 2) | g) ^ ((l15 >> 1) & 7)) * 16;
    const int aRd  = wm * 8192 + (l15 >> 1) * 128 + slot;           // + m*1024
    const int bRd  = 16384 + wn * 4096 + (l15 >> 1) * 128 + slot;   // + n*1024

    f32x4 acc[8][4] = {};

    auto readA = [&](char* cb, bf16x8 (&af)[8]) {
#pragma unroll
        for (int m = 0; m < 8; ++m) af[m] = *(const bf16x8*)(cb + aRd + m * 1024);
    };
    auto readB = [&](char* cb, bf16x8 (&bf)[4]) {
#pragma unroll
        for (int n = 0; n < 4; ++n) bf[n] = *(const bf16x8*)(cb + bRd + n * 1024);
    };

#define MFMA_CLUSTER(af_, bf_)                                                \
    {                                                                         \
        __builtin_amdgcn_s_setprio(1);                                        \
        _Pragma("unroll")                                                     \
        for (int m = 0; m < 8; ++m)                                           \
            _Pragma("unroll")                                                 \
            for (int n = 0; n < 4; ++n)                                       \
                acc[m][n] = __builtin_amdgcn_mfma_f32_16x16x32_bf16(          \
                    af_[m], bf_[n], acc[m][n], 0, 0, 0);                      \
        __builtin_amdgcn_s_setprio(0);                                        \
    }

    // ---- prologue: stage K-steps 0,1 ; FULL drain (both bufs must be complete) ----
    stageS(0);
    stageS(1);
    asm volatile("s_waitcnt vmcnt(0)" ::: "memory");
    __builtin_amdgcn_s_barrier();
    __builtin_amdgcn_sched_barrier(0);

#pragma unroll 1
    for (int body = 0; body < KSTEPS / 2; ++body) {
        const int t0 = 2 * body;
        char* c0 = smem + (t0 & 3) * BUFSZ;
        char* c1 = smem + ((t0 + 1) & 3) * BUFSZ;
        const bool st2 = (t0 + 2 < KSTEPS);
        const bool st3 = (t0 + 3 < KSTEPS);

        if (wm == 0) {
            // ===== E-role: R(t0) M(t0) R(t1) M(t1) =====
            bf16x8 af[8], bfr[4];
            readB(c0, bfr); readA(c0, af);
            if (st2) stageS(t0 + 2);
            __builtin_amdgcn_sched_barrier(0);
            MFMA_CLUSTER(af, bfr);
            __builtin_amdgcn_sched_barrier(0);
            readB(c1, bfr); readA(c1, af);
            if (st3) stageS(t0 + 3);
            __builtin_amdgcn_sched_barrier(0);
            MFMA_CLUSTER(af, bfr);
        } else {
            // ===== O-role: R(t0)+R_A(t1) M(t0) R_B(t1) M(t1) =====
            bf16x8 af0[8], bf0[4], af1[8], bf1[4];
            readB(c0, bf0); readA(c0, af0);
            if (st2) stageS(t0 + 2);
            readA(c1, af1);
            if (st3) stageS(t0 + 3);
            __builtin_amdgcn_sched_barrier(0);
            MFMA_CLUSTER(af0, bf0);
            __builtin_amdgcn_sched_barrier(0);
            readB(c1, bf1);
            __builtin_amdgcn_sched_barrier(0);
            MFMA_CLUSTER(af1, bf1);
        }

        __builtin_amdgcn_sched_barrier(0);
        if (body + 1 < KSTEPS / 2) {
            // drain this body's stage(t0+2),(t0+3) (issued >=1 MFMA-cluster ago)
            asm volatile("s_waitcnt vmcnt(0)" ::: "memory");
            __builtin_amdgcn_s_barrier();
            __builtin_amdgcn_sched_barrier(0);
        }
    }
#undef MFMA_CLUSTER

    // ---- epilogue: C frag col = l15, row = g*4+j ----
    float cb2[4];
#pragma unroll
    for (int n = 0; n < 4; ++n) cb2[n] = conv_b[obase + wn * 64 + n * 16 + l15];
#pragma unroll
    for (int m = 0; m < 8; ++m) {
#pragma unroll
        for (int j = 0; j < 4; ++j) {
            int r = pixbase + wm * 128 + m * 16 + g * 4 + j;
            float* orow = out + (size_t)r * OUTC + obase + wn * 64 + l15;
#pragma unroll
            for (int n = 0; n < 4; ++n)
                orow[n * 16] = acc[m][n][j] + cb2[n];
        }
    }
}

// ---------------- launch ----------------
extern "C" void kernel_launch(void* const* d_in, const int* in_sizes, int n_in,
                              void* d_out, int out_size, void* d_ws, size_t ws_size,
                              hipStream_t stream) {
    const float* x      = (const float*)d_in[0];
    const float* w_sp   = (const float*)d_in[1];
    const float* w_pw   = (const float*)d_in[2];
    const float* bias   = (const float*)d_in[3];
    const float* conv_w = (const float*)d_in[4];
    const float* conv_b = (const float*)d_in[5];
    float* out = (float*)d_out;

    char* ws = (char*)d_ws;
    __hip_bfloat16* wT    = (__hip_bfloat16*)(ws);
    float*          ps    = (float*)(ws + 4718592);
    float*          pq    = (float*)(ws + 4718592 + 524288);
    float*          scale = (float*)(ws + 5767168);
    float*          shift = (float*)(ws + 5775360);
    __hip_bfloat16* tpad  = (__hip_bfloat16*)(ws + 5783552);

    k0_transpose_w<<<dim3(9, 4, 16), 256, 0, stream>>>(conv_w, wT);
    k1_stats_partial<<<Bn * Hn, 1024, 0, stream>>>(x, ps, pq);
    k2_stats_final<<<Bn, 1024, 0, stream>>>(ps, pq, scale, shift);
    k3_dwconv<<<Bn * HPAD * 4, 256, 0, stream>>>(x, w_sp, w_pw, bias, scale, shift, tpad);
    k4_gemm<<<512, 512, 0, stream>>>(tpad, wT, conv_b, out);
}